// Round 1
// 14631.454 us; speedup vs baseline: 1.1734x; 1.1734x over previous
//
#include <hip/hip_runtime.h>

constexpr int TT = 2048, BB = 128, DD = 100, HH = 1024;
constexpr int NTHREADS = 512;

typedef __attribute__((ext_vector_type(8))) short s8;
typedef __attribute__((ext_vector_type(4))) float f4;

__device__ __forceinline__ s8 load_s8_sc1(const void* p) {
    s8 v; asm volatile("global_load_dwordx4 %0, %1, off sc0 sc1" : "=v"(v) : "v"(p) : "memory"); return v;
}
__device__ __forceinline__ f4 load_f4_asm(const void* p) {
    f4 v; asm volatile("global_load_dwordx4 %0, %1, off" : "=v"(v) : "v"(p) : "memory"); return v;
}
__device__ __forceinline__ void store_u16_sc1(void* p, unsigned v) {
    asm volatile("global_store_short %0, %1, off sc0 sc1" :: "v"(p), "v"(v) : "memory");
}
// waitcnt chained through the consumer's dataflow (round-3/4 lesson: a bare
// waitcnt asm does NOT stop the scheduler from hoisting consumers above it)
#define WAIT2(n, a, b) asm volatile("s_waitcnt vmcnt(" #n ")" : "+v"(a), "+v"(b) :: "memory")
// order-only tie: pins consumers of (a,b) after this program point without
// emitting an instruction. HW validity of (a,b) comes from the poll's
// compiler-inserted vmcnt(0) (FIFO retire of older x-loads).
#define TIE2(a, b) asm volatile("" : "+v"(a), "+v"(b) :: "memory")

__device__ __forceinline__ unsigned bf16_rne(float v) {
    unsigned u = __float_as_uint(v);
    return (u + 0x7FFFu + ((u >> 16) & 1u)) >> 16;
}
__device__ __forceinline__ void split2(float v, unsigned& hi, unsigned& lo) {
    hi = bf16_rne(v);
    lo = bf16_rne(v - __uint_as_float(hi << 16));
}
__device__ __forceinline__ int flag_ld(const int* p) {
    return __hip_atomic_load(p, __ATOMIC_RELAXED, __HIP_MEMORY_SCOPE_AGENT);
}
__device__ __forceinline__ void flag_st(int* p, int v) {
    __hip_atomic_store(p, v, __ATOMIC_RELAXED, __HIP_MEMORY_SCOPE_AGENT);
}
__device__ __forceinline__ void pack8(f4 a, f4 b, s8& h8, s8& l8) {
    float vs[8] = {a.x, a.y, a.z, a.w, b.x, b.y, b.z, b.w};
    #pragma unroll
    for (int j = 0; j < 8; ++j) {
        unsigned h_, l_;
        split2(vs[j], h_, l_);
        ((unsigned short*)&h8)[j] = (unsigned short)h_;
        ((unsigned short*)&l8)[j] = (unsigned short)l_;
    }
}

#define MFMA(a, b, c) __builtin_amdgcn_mfma_f32_16x16x32_bf16((a), (b), (c), 0, 0, 0)

__global__ __launch_bounds__(NTHREADS, 1)
void rnn_pc(const float* __restrict__ x, const float* __restrict__ W_ih,
            const float* __restrict__ b_ih, const float* __restrict__ W_hh,
            const float* __restrict__ b_hh, const float* __restrict__ W_out,
            const float* __restrict__ b_out, float* __restrict__ out,
            float* __restrict__ ws)
{
    // [t&1][tl][batch16][col*9 + cSel], row stride 146, col stride 9:
    // write bank = (8*quad + 9*mrow + K) mod 32 -> exact 2-way (free, m136).
    __shared__ float sRed[2 * 2 * 16 * 146];

    const int tid = threadIdx.x;
    const int g = blockIdx.x & 7;          // batch group
    const int m = blockIdx.x >> 3;         // h-slice member 0..31
    const int b0 = g * 16;
    const int h0r = m * 32;

    const int lane = tid & 63;
    const int wave = tid >> 6;             // = cSel, 8-way K split
    const int cSel = wave;
    const bool isx = (wave >= 4);          // waves 4..7 also handle the x-projection
    const int mrow = lane & 15;
    const int quad = lane >> 4;

    unsigned short* hp = (unsigned short*)ws;
    unsigned short* hHi[2] = { hp, hp + BB * HH };
    unsigned short* hLo[2] = { hp + 2 * BB * HH, hp + 3 * BB * HH };
    int* fl = (int*)(hp + 4 * BB * HH);
    int* produced = fl;                    // [32 member][8 wave][8 group]
    int* slots    = fl + 2048;             // [32][8]

    // ---- one-time: W_hh fragments into registers (64 VGPR/lane) ----
    s8 Bh[4][2], Bl[4][2];
    #pragma unroll
    for (int p = 0; p < 4; ++p)
        #pragma unroll
        for (int tl = 0; tl < 2; ++tl) {
            const float* wr = W_hh + (size_t)(h0r + tl * 16 + mrow) * HH
                            + p * 256 + cSel * 32 + quad * 8;
            pack8(*(const f4*)wr, *(const f4*)(wr + 4), Bh[p][tl], Bl[p][tl]);
        }
    // W_ih fragments (x-waves only), K padded 100->128
    s8 Ih[2] = {}, Il[2] = {};
    const int kx = (cSel - 4) * 32 + quad * 8;
    const bool xm1 = isx && (kx <= 96);    // first f4 fully < 100
    const bool xm2 = isx && (kx <= 92);    // second f4 fully < 100
    if (isx) {
        #pragma unroll
        for (int tl = 0; tl < 2; ++tl) {
            const float* ir = W_ih + (size_t)(h0r + tl * 16 + mrow) * DD;
            f4 v1 = xm1 ? *(const f4*)(ir + kx) : f4{0.f, 0.f, 0.f, 0.f};
            f4 v2 = xm2 ? *(const f4*)(ir + kx + 4) : f4{0.f, 0.f, 0.f, 0.f};
            pack8(v1, v2, Ih[tl], Il[tl]);
        }
    }
    const float myBias = b_ih[h0r + (tid & 31)] + b_hh[h0r + (tid & 31)];

    // ---- init h0 slice (both planes) + per-wave produced flags ----
    {
        int bb = tid >> 5, hh2 = tid & 31;
        store_u16_sc1(hHi[0] + (size_t)(b0 + bb) * HH + h0r + hh2, 0u);
        store_u16_sc1(hLo[0] + (size_t)(b0 + bb) * HH + h0r + hh2, 0u);
        if (tid < 8) flag_st(&produced[(m * 8 + tid) * 8 + g], 1);
    }
    asm volatile("s_waitcnt vmcnt(0)" ::: "memory");
    __syncthreads();
    if (tid == 0) flag_st(&slots[m * 8 + g], 1);
    for (;;) { bool ok = flag_ld(&slots[(lane & 31) * 8 + g]) >= 1; if (__ballot(ok) == ~0ull) break; }
    asm volatile("" ::: "memory");
    __syncthreads();

    // wave cSel phase p reads member 8p+cSel; needs all 8 producer waves of it.
    // lanes 0..31 cover 4 members x 8 waves; lanes 32..63 duplicate.
    const int pollIdx = (((lane & 3) * 8 + cSel) * 8 + ((lane >> 2) & 7)) * 8 + g;

    int cb = 0;
    for (int t = 0; t < TT; ++t) {
        const unsigned short* cHi = hHi[cb];
        const unsigned short* cLo = hLo[cb];
        unsigned short* nHi = hHi[cb ^ 1];
        unsigned short* nLo = hLo[cb ^ 1];

        // ---- x loads issued BEFORE the poll: HBM/L2 latency hides under it ----
        f4 xv1{}, xv2{};
        if (isx) {
            const float* xr = x + (size_t)t * BB * DD + (size_t)(b0 + mrow) * DD;
            xv1 = load_f4_asm(xr + (xm1 ? kx : 0));
            xv2 = load_f4_asm(xr + (xm2 ? kx + 4 : 0));
        }
        // ---- fine-grained per-(member,wave) producer poll ----
        for (;;) { bool ok = flag_ld(&produced[pollIdx]) >= t + 1; if (__ballot(ok) == ~0ull) break; }
        asm volatile("" ::: "memory");

        // ---- A-plane loads (h state via LLC); FIFO: exactly these 8 in flight ----
        s8 Ahi[4], Alo[4];
        #pragma unroll
        for (int p = 0; p < 4; ++p) {
            const size_t ao = (size_t)(b0 + mrow) * HH + p * 256 + cSel * 32 + quad * 8;
            Ahi[p] = load_s8_sc1(cHi + ao);
            Alo[p] = load_s8_sc1(cLo + ao);
        }

        f4 acc0 = {0.f, 0.f, 0.f, 0.f}, acc1 = {0.f, 0.f, 0.f, 0.f};
        // x-projection first: pack8 + 6 MFMAs execute in the A-load shadow.
        if (isx) {
            TIE2(xv1, xv2);
            if (!xm1) xv1 = f4{0.f, 0.f, 0.f, 0.f};
            if (!xm2) xv2 = f4{0.f, 0.f, 0.f, 0.f};
            s8 xh, xl; pack8(xv1, xv2, xh, xl);
            acc0 = MFMA(xh, Ih[0], acc0); acc1 = MFMA(xh, Ih[1], acc1);
            acc0 = MFMA(xh, Il[0], acc0); acc1 = MFMA(xh, Il[1], acc1);
            acc0 = MFMA(xl, Ih[0], acc0); acc1 = MFMA(xl, Ih[1], acc1);
        }
        WAIT2(6, Ahi[0], Alo[0]);
        acc0 = MFMA(Ahi[0], Bh[0][0], acc0); acc1 = MFMA(Ahi[0], Bh[0][1], acc1);
        acc0 = MFMA(Ahi[0], Bl[0][0], acc0); acc1 = MFMA(Ahi[0], Bl[0][1], acc1);
        acc0 = MFMA(Alo[0], Bh[0][0], acc0); acc1 = MFMA(Alo[0], Bh[0][1], acc1);
        WAIT2(4, Ahi[1], Alo[1]);
        acc0 = MFMA(Ahi[1], Bh[1][0], acc0); acc1 = MFMA(Ahi[1], Bh[1][1], acc1);
        acc0 = MFMA(Ahi[1], Bl[1][0], acc0); acc1 = MFMA(Ahi[1], Bl[1][1], acc1);
        acc0 = MFMA(Alo[1], Bh[1][0], acc0); acc1 = MFMA(Alo[1], Bh[1][1], acc1);
        WAIT2(2, Ahi[2], Alo[2]);
        acc0 = MFMA(Ahi[2], Bh[2][0], acc0); acc1 = MFMA(Ahi[2], Bh[2][1], acc1);
        acc0 = MFMA(Ahi[2], Bl[2][0], acc0); acc1 = MFMA(Ahi[2], Bl[2][1], acc1);
        acc0 = MFMA(Alo[2], Bh[2][0], acc0); acc1 = MFMA(Alo[2], Bh[2][1], acc1);
        WAIT2(0, Ahi[3], Alo[3]);
        acc0 = MFMA(Ahi[3], Bh[3][0], acc0); acc1 = MFMA(Ahi[3], Bh[3][1], acc1);
        acc0 = MFMA(Ahi[3], Bl[3][0], acc0); acc1 = MFMA(Ahi[3], Bl[3][1], acc1);
        acc0 = MFMA(Alo[3], Bh[3][0], acc0); acc1 = MFMA(Alo[3], Bh[3][1], acc1);

        // ---- partial-sum exchange: double-buffered, conflict-free strides ----
        // C/D layout col=lane&15 (ncol), row=quad*4+r (batch)
        const int sb = t & 1;
        #pragma unroll
        for (int r = 0; r < 4; ++r) {
            const int row = quad * 4 + r;
            sRed[((sb * 2 + 0) * 16 + row) * 146 + mrow * 9 + cSel] = acc0[r];
            sRed[((sb * 2 + 1) * 16 + row) * 146 + mrow * 9 + cSel] = acc1[r];
        }
        __syncthreads();   // the ONLY barrier per step
        {
            const int bb = tid >> 5, hh2 = tid & 31;
            const int tl = hh2 >> 4, col = hh2 & 15;
            const float* rb = &sRed[((sb * 2 + tl) * 16 + bb) * 146 + col * 9];
            float sum = ((rb[0] + rb[1]) + (rb[2] + rb[3]))
                      + ((rb[4] + rb[5]) + (rb[6] + rb[7])) + myBias;
            float hv = tanhf(sum);
            unsigned hi_, lo_; split2(hv, hi_, lo_);
            // Buffer-reuse safety (consumed flags removed): before any h-store,
            // this block's 8 waves have collectively observed ALL 32 members'
            // waves >= t+1 (their step t-1 A-loads retired before those flags),
            // so overwriting the h_{t-1} buffer is race-free.
            store_u16_sc1(nHi + (size_t)(b0 + bb) * HH + h0r + hh2, hi_);
            store_u16_sc1(nLo + (size_t)(b0 + bb) * HH + h0r + hh2, lo_);
        }
        asm volatile("s_waitcnt vmcnt(0)" ::: "memory");   // per-wave: own stores at LLC
        if (lane == 0) flag_st(&produced[(m * 8 + wave) * 8 + g], t + 2);
        cb ^= 1;
    }

    // ---- final projection: h_TT in buffer 0 (TT even) ----
    if (m == 0) {
        const int ms = lane & 31, wb = (lane >> 5) * 4;
        for (;;) {
            bool ok = true;
            #pragma unroll
            for (int j = 0; j < 4; ++j)
                ok &= flag_ld(&produced[(ms * 8 + wb + j) * 8 + g]) >= TT + 1;
            if (__ballot(ok) == ~0ull) break;
        }
        asm volatile("" ::: "memory");
        int bb = tid >> 5, part = tid & 31;
        const unsigned short* hr = hHi[0] + (size_t)(b0 + bb) * HH;
        const unsigned short* lr = hLo[0] + (size_t)(b0 + bb) * HH;
        float s = 0.f;
        #pragma unroll
        for (int q = 0; q < 4; ++q) {
            int k = part * 32 + q * 8;
            s8 h8 = load_s8_sc1(hr + k);
            s8 l8 = load_s8_sc1(lr + k);
            WAIT2(0, h8, l8);
            #pragma unroll
            for (int j = 0; j < 8; ++j) {
                float hvj = __uint_as_float(((unsigned)((unsigned short*)&h8)[j]) << 16)
                          + __uint_as_float(((unsigned)((unsigned short*)&l8)[j]) << 16);
                s = fmaf(hvj, W_out[k + j], s);
            }
        }
        s += __shfl_xor(s, 1); s += __shfl_xor(s, 2); s += __shfl_xor(s, 4);
        s += __shfl_xor(s, 8); s += __shfl_xor(s, 16);
        if (part == 0) out[b0 + bb] = tanhf(s + b_out[0]);
    }
}

extern "C" void kernel_launch(void* const* d_in, const int* in_sizes, int n_in,
                              void* d_out, int out_size, void* d_ws, size_t ws_size,
                              hipStream_t stream) {
    const float* x     = (const float*)d_in[0];
    const float* W_ih  = (const float*)d_in[1];
    const float* b_ih  = (const float*)d_in[2];
    const float* W_hh  = (const float*)d_in[3];
    const float* b_hh  = (const float*)d_in[4];
    const float* W_out = (const float*)d_in[5];
    const float* b_out = (const float*)d_in[6];
    float* out = (float*)d_out;
    float* ws  = (float*)d_ws;

    void* args[] = {&x, &W_ih, &b_ih, &W_hh, &b_hh, &W_out, &b_out, &out, &ws};
    hipLaunchCooperativeKernel((void*)rnn_pc, dim3(256), dim3(NTHREADS), args, 0, stream);
}

// Round 4
// 6390.447 us; speedup vs baseline: 2.6865x; 2.2896x over previous
//
#include <hip/hip_runtime.h>

constexpr int TT = 2048, BB = 128, DD = 100, HH = 1024;
constexpr int NTHREADS = 512;

typedef __attribute__((ext_vector_type(8))) short s8;
typedef __attribute__((ext_vector_type(4))) float f4;

// ---- LOADS: one encoding everywhere, the R1-proven coherent one (sc0 sc1).
__device__ __forceinline__ s8 load_s8_sc1(const void* p) {
    s8 v; asm volatile("global_load_dwordx4 %0, %1, off sc0 sc1" : "=v"(v) : "v"(p) : "memory"); return v;
}
__device__ __forceinline__ f4 load_f4_asm(const void* p) {
    f4 v; asm volatile("global_load_dwordx4 %0, %1, off" : "=v"(v) : "v"(p) : "memory"); return v;
}
// ---- STORES: scope-templated. SC1=true -> write-through IF$ (R1-proven).
// ---- SC1=false (LOCAL) -> sc0 only: line stays DIRTY in the group's own L2.
template<bool SC1> __device__ __forceinline__ void store_u16g(void* p, unsigned v) {
    if constexpr (SC1) asm volatile("global_store_short %0, %1, off sc0 sc1" :: "v"(p), "v"(v) : "memory");
    else               asm volatile("global_store_short %0, %1, off sc0"     :: "v"(p), "v"(v) : "memory");
}
template<bool SC1> __device__ __forceinline__ void flag_stg(int* p, int v) {
    if constexpr (SC1) asm volatile("global_store_dword %0, %1, off sc0 sc1" :: "v"(p), "v"(v) : "memory");
    else               asm volatile("global_store_dword %0, %1, off sc0"     :: "v"(p), "v"(v) : "memory");
}
#define WAIT2(n, a, b) asm volatile("s_waitcnt vmcnt(" #n ")" : "+v"(a), "+v"(b) :: "memory")
#define TIE2(a, b) asm volatile("" : "+v"(a), "+v"(b) :: "memory")

__device__ __forceinline__ unsigned bf16_rne(float v) {
    unsigned u = __float_as_uint(v);
    return (u + 0x7FFFu + ((u >> 16) & 1u)) >> 16;
}
__device__ __forceinline__ void split2(float v, unsigned& hi, unsigned& lo) {
    hi = bf16_rne(v);
    lo = bf16_rne(v - __uint_as_float(hi << 16));
}
// agent-scope atomic load/store (sc1 path) — R1-proven for polling in BOTH modes:
// loads bypass L1, hit valid/dirty L2 lines, see fresh data.
__device__ __forceinline__ int flag_ld(const int* p) {
    return __hip_atomic_load(p, __ATOMIC_RELAXED, __HIP_MEMORY_SCOPE_AGENT);
}
__device__ __forceinline__ void flag_st(int* p, int v) {
    __hip_atomic_store(p, v, __ATOMIC_RELAXED, __HIP_MEMORY_SCOPE_AGENT);
}
__device__ __forceinline__ void pack8(f4 a, f4 b, s8& h8, s8& l8) {
    float vs[8] = {a.x, a.y, a.z, a.w, b.x, b.y, b.z, b.w};
    #pragma unroll
    for (int j = 0; j < 8; ++j) {
        unsigned h_, l_;
        split2(vs[j], h_, l_);
        ((unsigned short*)&h8)[j] = (unsigned short)h_;
        ((unsigned short*)&l8)[j] = (unsigned short)l_;
    }
}

#define MFMA(a, b, c) __builtin_amdgcn_mfma_f32_16x16x32_bf16((a), (b), (c), 0, 0, 0)

template<bool SC1>
__device__ __forceinline__ void rnn_loop(
    int g, int m,
    const float* __restrict__ x, const float* __restrict__ W_out,
    const float* __restrict__ b_out, float* __restrict__ out,
    float* __restrict__ ws, float* sRed,
    const s8 (&Bh)[4][2], const s8 (&Bl)[4][2], const s8 (&Ih)[2], const s8 (&Il)[2],
    float myBias)
{
    const int tid = threadIdx.x;
    const int b0 = g * 16;
    const int h0r = m * 32;
    const int lane = tid & 63;
    const int wave = tid >> 6;
    const int cSel = wave;
    const bool isx = (wave >= 4);
    const int mrow = lane & 15;
    const int quad = lane >> 4;
    const int kx = (cSel - 4) * 32 + quad * 8;
    const bool xm1 = isx && (kx <= 96);
    const bool xm2 = isx && (kx <= 92);

    unsigned short* hp = (unsigned short*)ws;
    unsigned short* hHi[2] = { hp, hp + BB * HH };
    unsigned short* hLo[2] = { hp + 2 * BB * HH, hp + 3 * BB * HH };
    int* fl = (int*)(hp + 4 * BB * HH);
    int* produced = fl;                    // [8 group][32 member][8 wave] — group-exclusive lines

    // ---- init h0 slice + produced flags with mode-matched STORE scope ----
    // (consumers' t=0 polls gate every h0 read; flag stored after vmcnt(0)+barrier
    //  so flag>=1 implies the h0 slice is visible at the mode's coherence point)
    {
        int bb = tid >> 5, hh2 = tid & 31;
        store_u16g<SC1>(hHi[0] + (size_t)(b0 + bb) * HH + h0r + hh2, 0u);
        store_u16g<SC1>(hLo[0] + (size_t)(b0 + bb) * HH + h0r + hh2, 0u);
    }
    asm volatile("s_waitcnt vmcnt(0)" ::: "memory");
    __syncthreads();
    if (tid < 8) flag_stg<SC1>(&produced[g * 256 + m * 8 + tid], 1);

    // wave cSel phase p reads member 8p+cSel; needs all 8 producer waves of it.
    const int pollIdx = g * 256 + ((lane & 3) * 8 + cSel) * 8 + ((lane >> 2) & 7);

    int cb = 0;
    for (int t = 0; t < TT; ++t) {
        const unsigned short* cHi = hHi[cb];
        const unsigned short* cLo = hLo[cb];
        unsigned short* nHi = hHi[cb ^ 1];
        unsigned short* nLo = hLo[cb ^ 1];

        // ---- x loads issued BEFORE the poll: latency hides under it ----
        f4 xv1{}, xv2{};
        if (isx) {
            const float* xr = x + (size_t)t * BB * DD + (size_t)(b0 + mrow) * DD;
            xv1 = load_f4_asm(xr + (xm1 ? kx : 0));
            xv2 = load_f4_asm(xr + (xm2 ? kx + 4 : 0));
        }
        // ---- fine-grained per-(member,wave) producer poll (R1-proven atomic) ----
        for (;;) { bool ok = flag_ld(&produced[pollIdx]) >= t + 1; if (__ballot(ok) == ~0ull) break; }
        asm volatile("" ::: "memory");

        // ---- A-plane loads; FIFO: exactly these 8 in flight during MFMA section ----
        s8 Ahi[4], Alo[4];
        #pragma unroll
        for (int p = 0; p < 4; ++p) {
            const size_t ao = (size_t)(b0 + mrow) * HH + p * 256 + cSel * 32 + quad * 8;
            Ahi[p] = load_s8_sc1(cHi + ao);
            Alo[p] = load_s8_sc1(cLo + ao);
        }

        f4 acc0 = {0.f, 0.f, 0.f, 0.f}, acc1 = {0.f, 0.f, 0.f, 0.f};
        // x-projection first: pack8 + 6 MFMAs execute in the A-load shadow.
        if (isx) {
            TIE2(xv1, xv2);   // HW validity from the poll's internal vmcnt wait
            if (!xm1) xv1 = f4{0.f, 0.f, 0.f, 0.f};
            if (!xm2) xv2 = f4{0.f, 0.f, 0.f, 0.f};
            s8 xh, xl; pack8(xv1, xv2, xh, xl);
            acc0 = MFMA(xh, Ih[0], acc0); acc1 = MFMA(xh, Ih[1], acc1);
            acc0 = MFMA(xh, Il[0], acc0); acc1 = MFMA(xh, Il[1], acc1);
            acc0 = MFMA(xl, Ih[0], acc0); acc1 = MFMA(xl, Ih[1], acc1);
        }
        WAIT2(6, Ahi[0], Alo[0]);
        acc0 = MFMA(Ahi[0], Bh[0][0], acc0); acc1 = MFMA(Ahi[0], Bh[0][1], acc1);
        acc0 = MFMA(Ahi[0], Bl[0][0], acc0); acc1 = MFMA(Ahi[0], Bl[0][1], acc1);
        acc0 = MFMA(Alo[0], Bh[0][0], acc0); acc1 = MFMA(Alo[0], Bh[0][1], acc1);
        WAIT2(4, Ahi[1], Alo[1]);
        acc0 = MFMA(Ahi[1], Bh[1][0], acc0); acc1 = MFMA(Ahi[1], Bh[1][1], acc1);
        acc0 = MFMA(Ahi[1], Bl[1][0], acc0); acc1 = MFMA(Ahi[1], Bl[1][1], acc1);
        acc0 = MFMA(Alo[1], Bh[1][0], acc0); acc1 = MFMA(Alo[1], Bh[1][1], acc1);
        WAIT2(2, Ahi[2], Alo[2]);
        acc0 = MFMA(Ahi[2], Bh[2][0], acc0); acc1 = MFMA(Ahi[2], Bh[2][1], acc1);
        acc0 = MFMA(Ahi[2], Bl[2][0], acc0); acc1 = MFMA(Ahi[2], Bl[2][1], acc1);
        acc0 = MFMA(Alo[2], Bh[2][0], acc0); acc1 = MFMA(Alo[2], Bh[2][1], acc1);
        WAIT2(0, Ahi[3], Alo[3]);
        acc0 = MFMA(Ahi[3], Bh[3][0], acc0); acc1 = MFMA(Ahi[3], Bh[3][1], acc1);
        acc0 = MFMA(Ahi[3], Bl[3][0], acc0); acc1 = MFMA(Ahi[3], Bl[3][1], acc1);
        acc0 = MFMA(Alo[3], Bh[3][0], acc0); acc1 = MFMA(Alo[3], Bh[3][1], acc1);

        // ---- partial-sum exchange: double-buffered, ~2-way-conflict strides ----
        const int sb = t & 1;
        #pragma unroll
        for (int r = 0; r < 4; ++r) {
            const int row = quad * 4 + r;
            sRed[((sb * 2 + 0) * 16 + row) * 146 + mrow * 9 + cSel] = acc0[r];
            sRed[((sb * 2 + 1) * 16 + row) * 146 + mrow * 9 + cSel] = acc1[r];
        }
        __syncthreads();   // the ONLY barrier per step
        {
            const int bb = tid >> 5, hh2 = tid & 31;
            const int tl = hh2 >> 4, col = hh2 & 15;
            const float* rb = &sRed[((sb * 2 + tl) * 16 + bb) * 146 + col * 9];
            float sum = ((rb[0] + rb[1]) + (rb[2] + rb[3]))
                      + ((rb[4] + rb[5]) + (rb[6] + rb[7])) + myBias;
            float hv = tanhf(sum);
            unsigned hi_, lo_; split2(hv, hi_, lo_);
            // Buffer-reuse safety: this block's 8 waves collectively observed all
            // 32 members' waves >= t+1 before any h-store (their step t-1 A-loads
            // retired first), so overwriting the h_{t-1} buffer is race-free.
            store_u16g<SC1>(nHi + (size_t)(b0 + bb) * HH + h0r + hh2, hi_);
            store_u16g<SC1>(nLo + (size_t)(b0 + bb) * HH + h0r + hh2, lo_);
        }
        asm volatile("s_waitcnt vmcnt(0)" ::: "memory");   // own stores at coherence point
        if (lane == 0) flag_stg<SC1>(&produced[g * 256 + m * 8 + wave], t + 2);
        cb ^= 1;
    }

    // ---- final projection: h_TT in buffer 0 (TT even) ----
    if (m == 0) {
        const int ms = lane & 31, wb = (lane >> 5) * 4;
        for (;;) {
            bool ok = true;
            #pragma unroll
            for (int j = 0; j < 4; ++j)
                ok &= flag_ld(&produced[g * 256 + ms * 8 + wb + j]) >= TT + 1;
            if (__ballot(ok) == ~0ull) break;
        }
        asm volatile("" ::: "memory");
        int bb = tid >> 5, part = tid & 31;
        const unsigned short* hr = hHi[0] + (size_t)(b0 + bb) * HH;
        const unsigned short* lr = hLo[0] + (size_t)(b0 + bb) * HH;
        float s = 0.f;
        #pragma unroll
        for (int q = 0; q < 4; ++q) {
            int k = part * 32 + q * 8;
            s8 h8 = load_s8_sc1(hr + k);
            s8 l8 = load_s8_sc1(lr + k);
            WAIT2(0, h8, l8);
            #pragma unroll
            for (int j = 0; j < 8; ++j) {
                float hvj = __uint_as_float(((unsigned)((unsigned short*)&h8)[j]) << 16)
                          + __uint_as_float(((unsigned)((unsigned short*)&l8)[j]) << 16);
                s = fmaf(hvj, W_out[k + j], s);
            }
        }
        s += __shfl_xor(s, 1); s += __shfl_xor(s, 2); s += __shfl_xor(s, 4);
        s += __shfl_xor(s, 8); s += __shfl_xor(s, 16);
        if (part == 0) out[b0 + bb] = tanhf(s + b_out[0]);
    }
}

__global__ __launch_bounds__(NTHREADS, 1)
void rnn_pc(const float* __restrict__ x, const float* __restrict__ W_ih,
            const float* __restrict__ b_ih, const float* __restrict__ W_hh,
            const float* __restrict__ b_hh, const float* __restrict__ W_out,
            const float* __restrict__ b_out, float* __restrict__ out,
            float* __restrict__ ws)
{
    // dynamic LDS: ONE 37376-byte buffer shared by both template instantiations
    extern __shared__ float sRed[];

    const int tid = threadIdx.x;
    const int bid = blockIdx.x;
    const int lane = tid & 63;
    const int cSel = tid >> 6;
    const bool isx = (cSel >= 4);
    const int mrow = lane & 15;
    const int quad = lane >> 4;

    unsigned short* hp = (unsigned short*)ws;
    int* fl = (int*)(hp + 4 * BB * HH);
    int* ready1 = fl + 2048;               // [256]: xcd+1 per blockIdx (agent scope only)

    // ---- rendezvous: publish XCC_ID, learn the actual block->XCD placement ----
    // hwreg(HW_REG_XCC_ID=20, offset 0, size 4)
    const int myXcd = (int)__builtin_amdgcn_s_getreg(20 | (0 << 6) | (3 << 11));
    if (tid == 0) flag_st(&ready1[bid], myXcd + 1);
    for (;;) {
        bool ok = true;
        #pragma unroll
        for (int j = 0; j < 4; ++j) ok &= (flag_ld(&ready1[lane + 64 * j]) >= 1);
        if (__ballot(ok) == ~0ull) break;
    }
    asm volatile("" ::: "memory");

    // ---- adaptive grouping: if every XCD holds exactly 32 blocks, derive
    // (g,m) from the real placement (g = xcd, m = rank within xcd). Any
    // imbalance or bogus XCC_ID -> proven sc1 fallback with static labels.
    unsigned c03 = 0, c47 = 0; int rank = 0; bool bad = false;
    #pragma unroll
    for (int j = 0; j < 4; ++j) {
        int idx = lane + 64 * j;
        int e = flag_ld(&ready1[idx]) - 1;
        if (e < 0 || e > 7) bad = true;
        else if (e < 4) c03 += 1u << (8 * e);
        else            c47 += 1u << (8 * (e - 4));
        if (e == myXcd && idx < bid) ++rank;
    }
    #pragma unroll
    for (int s = 1; s < 64; s <<= 1) {
        c03 += __shfl_xor(c03, s);
        c47 += __shfl_xor(c47, s);
        rank += __shfl_xor(rank, s);
    }
    const bool localXCD = (c03 == 0x20202020u) && (c47 == 0x20202020u)
                          && (__ballot(bad) == 0ull);
    const int g = localXCD ? myXcd : (bid & 7);
    const int m = localXCD ? rank  : (bid >> 3);
    const int h0r = m * 32;

    // ---- one-time: W_hh fragments into registers ----
    s8 Bh[4][2], Bl[4][2];
    #pragma unroll
    for (int p = 0; p < 4; ++p)
        #pragma unroll
        for (int tl = 0; tl < 2; ++tl) {
            const float* wr = W_hh + (size_t)(h0r + tl * 16 + mrow) * HH
                            + p * 256 + cSel * 32 + quad * 8;
            pack8(*(const f4*)wr, *(const f4*)(wr + 4), Bh[p][tl], Bl[p][tl]);
        }
    s8 Ih[2] = {}, Il[2] = {};
    const int kx = (cSel - 4) * 32 + quad * 8;
    const bool xm1 = isx && (kx <= 96);
    const bool xm2 = isx && (kx <= 92);
    if (isx) {
        #pragma unroll
        for (int tl = 0; tl < 2; ++tl) {
            const float* ir = W_ih + (size_t)(h0r + tl * 16 + mrow) * DD;
            f4 v1 = xm1 ? *(const f4*)(ir + kx) : f4{0.f, 0.f, 0.f, 0.f};
            f4 v2 = xm2 ? *(const f4*)(ir + kx + 4) : f4{0.f, 0.f, 0.f, 0.f};
            pack8(v1, v2, Ih[tl], Il[tl]);
        }
    }
    const float myBias = b_ih[h0r + (tid & 31)] + b_hh[h0r + (tid & 31)];

    if (localXCD)
        rnn_loop<false>(g, m, x, W_out, b_out, out, ws, sRed, Bh, Bl, Ih, Il, myBias);
    else
        rnn_loop<true>(g, m, x, W_out, b_out, out, ws, sRed, Bh, Bl, Ih, Il, myBias);
}

extern "C" void kernel_launch(void* const* d_in, const int* in_sizes, int n_in,
                              void* d_out, int out_size, void* d_ws, size_t ws_size,
                              hipStream_t stream) {
    const float* x     = (const float*)d_in[0];
    const float* W_ih  = (const float*)d_in[1];
    const float* b_ih  = (const float*)d_in[2];
    const float* W_hh  = (const float*)d_in[3];
    const float* b_hh  = (const float*)d_in[4];
    const float* W_out = (const float*)d_in[5];
    const float* b_out = (const float*)d_in[6];
    float* out = (float*)d_out;
    float* ws  = (float*)d_ws;

    void* args[] = {&x, &W_ih, &b_ih, &W_hh, &b_hh, &W_out, &b_out, &out, &ws};
    hipLaunchCooperativeKernel((void*)rnn_pc, dim3(256), dim3(NTHREADS), args,
                               2 * 2 * 16 * 146 * sizeof(float), stream);
}